// Round 4
// baseline (792.205 us; speedup 1.0000x reference)
//
#include <hip/hip_runtime.h>
#include <hip/hip_bf16.h>
#include <hip/hip_fp16.h>

#define H 2048
#define E 8
#define DFF 8192
#define NTOK 4096
#define NB 4  // H/512 scale blocks

typedef _Float16 f16x8 __attribute__((ext_vector_type(8)));
typedef float f32x4 __attribute__((ext_vector_type(4)));

#define AS1 __attribute__((address_space(1)))
#define AS3 __attribute__((address_space(3)))

__device__ __forceinline__ void gl_lds16(const void* g, void* l) {
    __builtin_amdgcn_global_load_lds((const AS1 unsigned int*)g,
                                     (AS3 unsigned int*)l, 16, 0, 0);
}

__device__ __forceinline__ float gelu_f(float x) {
    float u = 0.7978845608028654f * x * (1.0f + 0.044715f * x * x);
    float t = fabsf(u);
    float e = __expf(-2.0f * t);
    float th = (1.0f - e) / (1.0f + e);
    th = copysignf(th, u);
    return 0.5f * x * (1.0f + th);
}

// ---------------- router (fp32) + x -> fp16 cast ----------------
__global__ __launch_bounds__(256) void router_cast_kernel(
    const float* __restrict__ x, const float* __restrict__ rw,
    float* __restrict__ probs, _Float16* __restrict__ xh)
{
    int n = blockIdx.x, t = threadIdx.x;
    float acc[E];
#pragma unroll
    for (int e = 0; e < E; ++e) acc[e] = 0.f;
    const float* xr = x + (size_t)n * H;
#pragma unroll
    for (int k = 0; k < H / 256; ++k) {
        int h = t + k * 256;
        float xv = xr[h];
        xh[(size_t)n * H + h] = (_Float16)xv;
        const float4* r4 = reinterpret_cast<const float4*>(rw + (size_t)h * E);
        float4 a = r4[0], b = r4[1];
        acc[0] += xv * a.x; acc[1] += xv * a.y; acc[2] += xv * a.z; acc[3] += xv * a.w;
        acc[4] += xv * b.x; acc[5] += xv * b.y; acc[6] += xv * b.z; acc[7] += xv * b.w;
    }
#pragma unroll
    for (int e = 0; e < E; ++e) {
        float v = acc[e];
#pragma unroll
        for (int o = 32; o > 0; o >>= 1) v += __shfl_down(v, o, 64);
        acc[e] = v;
    }
    __shared__ float red[4][E];
    int wave = t >> 6, lane = t & 63;
    if (lane == 0) {
#pragma unroll
        for (int e = 0; e < E; ++e) red[wave][e] = acc[e];
    }
    __syncthreads();
    if (t == 0) {
        float lg[E];
        float mx = -1e30f;
#pragma unroll
        for (int e = 0; e < E; ++e) {
            lg[e] = red[0][e] + red[1][e] + red[2][e] + red[3][e];
            mx = fmaxf(mx, lg[e]);
        }
        float s = 0.f;
#pragma unroll
        for (int e = 0; e < E; ++e) { lg[e] = expf(lg[e] - mx); s += lg[e]; }
        float inv = 1.f / s;
#pragma unroll
        for (int e = 0; e < E; ++e) {
            float p = lg[e] * inv;
            p = __half2float(__float2half(p));
            probs[(size_t)n * E + e] = p;
        }
    }
}

// ---------------- transpose + cast fp32 [R,C] -> fp16 [C,R] ----------------
__global__ __launch_bounds__(256) void transpose_cast_kernel(
    const float* __restrict__ src, _Float16* __restrict__ dst, int R, int C)
{
    __shared__ float tile[32][33];
    int tx = threadIdx.x & 31, ty = threadIdx.x >> 5;
    int c0 = blockIdx.x * 32, r0 = blockIdx.y * 32;
#pragma unroll
    for (int i = ty; i < 32; i += 8)
        tile[i][tx] = src[(size_t)(r0 + i) * C + c0 + tx];
    __syncthreads();
#pragma unroll
    for (int i = ty; i < 32; i += 8)
        dst[(size_t)(c0 + i) * R + r0 + tx] = (_Float16)tile[tx][i];
}

// ---------------- NF4 dequant + expert mix -> moe (fp32) ----------------
__global__ __launch_bounds__(256) void moe_kernel(
    const int* __restrict__ nf4, const float* __restrict__ mean,
    const float* __restrict__ stdv, const float* __restrict__ cb,
    const float* __restrict__ probs, float* __restrict__ moe)
{
    int n = blockIdx.x, t = threadIdx.x;
    __shared__ float cbl[32];
    __shared__ float ps[E][NB];
    __shared__ float cmean[NB];
    if (t < 16) { float v = cb[t]; cbl[t] = v; cbl[t + 16] = v; }
    else if (t >= 32 && t < 64) {
        int e = (t - 32) >> 2, b = t & 3;
        ps[e][b] = probs[(size_t)n * E + e] * stdv[((size_t)n * E + e) * NB + b];
    } else if (t >= 64 && t < 68) {
        int b = t - 64; float s = 0.f;
        for (int e = 0; e < E; ++e)
            s += probs[(size_t)n * E + e] * mean[((size_t)n * E + e) * NB + b];
        cmean[b] = s;
    }
    __syncthreads();
    int cboff = (t & 1) << 4;
    const int* w = nf4 + (size_t)n * (E * H / 2);
    float2* outp = reinterpret_cast<float2*>(moe + (size_t)n * H);
#pragma unroll
    for (int k = 0; k < 4; ++k) {
        int j = t + k * 256;
        float psr[E];
#pragma unroll
        for (int e = 0; e < E; ++e) psr[e] = ps[e][k];
        float cm = cmean[k];
        float aL = cm, aH = cm;
#pragma unroll
        for (int e = 0; e < E; ++e) {
            int word = w[e * (H / 2) + j];
            aL += psr[e] * cbl[(word & 15) + cboff];
            aH += psr[e] * cbl[((word >> 4) & 15) + cboff];
        }
        outp[j] = make_float2(aL, aH);
    }
}

// ------- fp16 MFMA GEMM: 256x256, 2-phase/tile, reads one phase ahead ----
// C = A[M,K] * Bt[N,K]^T.  512 thr / 8 waves (2M x 4N, per-wave 128x64,
// acc[8][4]).  BK=64, LDS = 2 bufs x 64KB.  k-seg-major layout (verified
// conflict-free; per-lane GLOBAL addr provides the staging permutation,
// global_load_lds writes linearly).
// Per tile two MFMA phases of 32 MFMA/wave; every fragment group is ISSUED
// one cluster ahead of its consumption and retired by the compiler's own
// COUNTED lgkmcnt (no manual lgkmcnt(0) in front of MFMA) so LDS bursts
// process inside the MFMA pipe windows.  Only 2 barriers per tile:
//   P1(t): stage B(t+1)->Rn | read aH(t) | MFMA (iL,jH) then (iL,jL)
//   P2(t): lgkmcnt(0); bar#1 (buf-t reads done -> its region reusable)
//          stage A(t+2)->Rt | vmcnt(4) (tile t+1 landed, A(t+2) in flight)
//          bar#2 (buf-t+1 published)
//          read aL(t+1) | MFMA (iH,jH) | read bH(t+1) | MFMA (iH,jL)
//          | read bL(t+1)
// A leads by ~3 half-phases, B by ~2; vmcnt never waits on a fresh load.
// EPI 0: out = f16(gelu(acc)).
// EPI 1: split-K pair: ks==0 -> out = acc + addsrc; ks==1 -> aux = acc.
template <int EPI, int MAP>
__global__ __launch_bounds__(512, 2) void gemm8p_kernel(
    const _Float16* __restrict__ A, const _Float16* __restrict__ Bt,
    const float* __restrict__ addsrc, void* __restrict__ outv,
    float* __restrict__ aux, int K, int LDK, int N)
{
    __shared__ uint4 lds_u4[131072 / 16];   // 128 KB
    char* lds = (char*)lds_u4;
    char* R0 = lds;
    char* R1 = lds + 65536;

    int t = threadIdx.x;
    int id = blockIdx.x;
    int xcd = id & 7, chunk = id >> 3;
    int by, bx, ks = 0;
    if constexpr (MAP == 0) {
        by = (xcd & 1) * 8 + (chunk & 7);
        bx = (xcd >> 1) * 8 + (chunk >> 3);
    } else {
        by = (xcd >> 1) * 4 + (chunk & 3);
        bx = (xcd & 1) * 4 + ((chunk >> 2) & 3);
        ks = chunk >> 4;
    }
    int m0 = by * 256, n0 = bx * 256;
    int koff = ks * K;

    const unsigned short* sA = (const unsigned short*)A
        + (size_t)(m0 + (t & 255)) * LDK + koff + (t >> 8) * 8;
    const unsigned short* sB = (const unsigned short*)Bt
        + (size_t)(n0 + (t & 255)) * LDK + koff + (t >> 8) * 8;
    unsigned dstT = (unsigned)t * 16;

    int lane = t & 63, wave = t >> 6;
    int wr = wave >> 2, wc = wave & 3;      // 2M x 4N
    int mb = wr * 128, nb = wc * 64;
    int q = lane >> 4, m16 = lane & 15;

    unsigned aBase = (unsigned)(mb + m16) * 16u;
    unsigned bBase = 32768u + (unsigned)(nb + m16) * 16u;

    f32x4 acc[8][4] = {};
    f16x8 aLf[8], aHf[8], blf[4], bhf[4];

#define STG_A4(Wb, T) do { \
    _Pragma("unroll") for (int s = 0; s < 4; ++s) \
        gl_lds16(sA + (size_t)(T) * 64 + s * 16, (Wb) + s * 8192 + dstT); } while (0)
#define STG_B4(Wb, T) do { \
    _Pragma("unroll") for (int s = 0; s < 4; ++s) \
        gl_lds16(sB + (size_t)(T) * 64 + s * 16, (Wb) + 32768 + s * 8192 + dstT); } while (0)
#define RD_A(Rb, ih, dst) do { \
    _Pragma("unroll") for (int il = 0; il < 4; ++il) \
    _Pragma("unroll") for (int kh = 0; kh < 2; ++kh) \
        dst[il * 2 + kh] = *(const f16x8*)((Rb) + aBase + \
            (unsigned)(kh * 16384 + q * 4096 + (ih) * 1024 + il * 256)); } while (0)
#define RD_B(Rb, jh, dst) do { \
    _Pragma("unroll") for (int jl = 0; jl < 2; ++jl) \
    _Pragma("unroll") for (int kh = 0; kh < 2; ++kh) \
        dst[jl * 2 + kh] = *(const f16x8*)((Rb) + bBase + \
            (unsigned)(kh * 16384 + q * 4096 + (jh) * 512 + jl * 256)); } while (0)
#define MM(i0, j0, afr, bfr) do { \
    _Pragma("unroll") for (int il = 0; il < 4; ++il) \
    _Pragma("unroll") for (int jl = 0; jl < 2; ++jl) \
    _Pragma("unroll") for (int kh = 0; kh < 2; ++kh) \
        acc[(i0) + il][(j0) + jl] = __builtin_amdgcn_mfma_f32_16x16x32_f16( \
            afr[il * 2 + kh], bfr[jl * 2 + kh], acc[(i0) + il][(j0) + jl], 0, 0, 0); } while (0)
#define BARR  asm volatile("s_barrier" ::: "memory")
#define LGKM0 asm volatile("s_waitcnt lgkmcnt(0)" ::: "memory")
#define VMC4  asm volatile("s_waitcnt vmcnt(4)" ::: "memory")
#define VMC0  asm volatile("s_waitcnt vmcnt(0)" ::: "memory")
#define SCB   __builtin_amdgcn_sched_barrier(0)
#define SP1   __builtin_amdgcn_s_setprio(1)
#define SP0   __builtin_amdgcn_s_setprio(0)

    // prologue: A(0),B(0)->R0, A(1)->R1; drain tile 0; read its aL,bL,bH
    STG_A4(R0, 0);
    STG_B4(R0, 0);
    STG_A4(R1, 1);
    VMC4;
    BARR;
    RD_A(R0, 0, aLf);
    RD_B(R0, 0, blf);
    RD_B(R0, 1, bhf);

    int NIT = K / 128;
    for (int i = 0; i < NIT; ++i) {
        int tt = 2 * i, u = tt + 1;
        bool more = (i + 1 < NIT);

        // ---------- P1(t): tile t, iL quadrants ----------
        STG_B4(R1, u);
        RD_A(R0, 1, aHf);
        SCB;
        SP1; MM(0, 2, aLf, bhf); SCB; MM(0, 0, aLf, blf); SP0;
        // ---------- P2(t): tile t, iH quadrants ----------
        LGKM0;                         // aH(t) retired -> R0 fully read
        BARR;                          // #1: all waves done with R0
        if (more) STG_A4(R0, tt + 2);
        if (more) { VMC4; } else { VMC0; }   // tile t+1 landed
        BARR;                          // #2: R1 published
        SCB;
        RD_A(R1, 0, aLf);
        SCB; SP1; MM(4, 2, aHf, bhf); SCB;
        RD_B(R1, 1, bhf);
        SCB; MM(4, 0, aHf, blf); SP0; SCB;
        RD_B(R1, 0, blf);
        // ---------- P1(u): tile t+1, iL quadrants ----------
        if (more) STG_B4(R0, tt + 2);
        RD_A(R1, 1, aHf);
        SCB;
        SP1; MM(0, 2, aLf, bhf); SCB; MM(0, 0, aLf, blf); SP0;
        // ---------- P2(u): tile t+1, iH quadrants ----------
        LGKM0;                         // aH(u) retired -> R1 fully read
        BARR;                          // #1
        if (more) STG_A4(R1, tt + 3);
        if (more) { VMC4; } else { VMC0; }   // tile t+2 landed
        BARR;                          // #2: R0 (tile t+2) published
        SCB;
        if (more) RD_A(R0, 0, aLf);
        SCB; SP1; MM(4, 2, aHf, bhf); SCB;
        if (more) RD_B(R0, 1, bhf);
        SCB; MM(4, 0, aHf, blf); SP0; SCB;
        if (more) RD_B(R0, 0, blf);
    }

    // epilogue (verified C/D mapping: col=lane&15, row=q*4+rix)
#pragma unroll
    for (int i = 0; i < 8; ++i)
#pragma unroll
        for (int j = 0; j < 4; ++j) {
            int row = m0 + mb + i * 16 + q * 4;
            int col = n0 + nb + j * 16 + m16;
#pragma unroll
            for (int rix = 0; rix < 4; ++rix) {
                float v = acc[i][j][rix];
                size_t o = (size_t)(row + rix) * N + col;
                if constexpr (EPI == 0) {
                    ((_Float16*)outv)[o] = (_Float16)gelu_f(v);
                } else {
                    if (ks == 0) ((float*)outv)[o] = v + addsrc[o];
                    else         aux[o] = v;
                }
            }
        }
#undef STG_A4
#undef STG_B4
#undef RD_A
#undef RD_B
#undef MM
#undef BARR
#undef LGKM0
#undef VMC4
#undef VMC0
#undef SCB
#undef SP1
#undef SP0
}

// ---------------- split-K combine: out += part ----------------
__global__ __launch_bounds__(256) void combine_kernel(
    float* __restrict__ out, const float* __restrict__ part)
{
    size_t base = (size_t)blockIdx.x * 256 + threadIdx.x;
    const float4* p4 = (const float4*)part;
    float4* o4 = (float4*)out;
#pragma unroll
    for (int s = 0; s < 4; ++s) {
        size_t i = base + (size_t)s * 524288;   // 2048*256
        float4 a = o4[i], b = p4[i];
        o4[i] = make_float4(a.x + b.x, a.y + b.y, a.z + b.z, a.w + b.w);
    }
}

extern "C" void kernel_launch(void* const* d_in, const int* in_sizes, int n_in,
                              void* d_out, int out_size, void* d_ws, size_t ws_size,
                              hipStream_t stream) {
    const float* x    = (const float*)d_in[0];
    const float* rw   = (const float*)d_in[1];
    const int*   nf4  = (const int*)d_in[2];
    const float* mean = (const float*)d_in[3];
    const float* stdv = (const float*)d_in[4];
    const float* cb   = (const float*)d_in[5];
    const float* w1   = (const float*)d_in[6];
    const float* w2   = (const float*)d_in[7];
    float* out = (float*)d_out;

    char* ws = (char*)d_ws;
    float* probs      = (float*)ws;                          // 128 KB
    float* moe        = (float*)(ws + 131072);               // 32 MB
    _Float16* xh      = (_Float16*)(ws + 33685504);          // 16 MB  [NTOK,H]
    _Float16* w1t     = (_Float16*)(ws + 50462720);          // 32 MB  [DFF,H]
    _Float16* w2t     = (_Float16*)(ws + 84017152);          // 32 MB  [H,DFF]
    _Float16* hid     = (_Float16*)(ws + 117571584);         // 64 MB  [NTOK,DFF]
    // split-K partial buffer overlays w1t (dead after GEMM1): 32 MB fp32
    float* pbuf       = (float*)(ws + 50462720);

    router_cast_kernel<<<NTOK, 256, 0, stream>>>(x, rw, probs, xh);
    transpose_cast_kernel<<<dim3(DFF / 32, H / 32), 256, 0, stream>>>(w1, w1t, H, DFF);
    transpose_cast_kernel<<<dim3(H / 32, DFF / 32), 256, 0, stream>>>(w2, w2t, DFF, H);
    moe_kernel<<<NTOK, 256, 0, stream>>>(nf4, mean, stdv, cb, probs, moe);
    // hidden = gelu(x @ w1): 256x256 tiles, grid 16x32 -> 512 blocks (2 rounds)
    gemm8p_kernel<0, 0><<<512, 512, 0, stream>>>(xh, w1t, nullptr, (void*)hid,
                                                 nullptr, H, H, DFF);
    // out = moe + hidden @ w2, split-K=2: 256 blocks (1/CU)
    gemm8p_kernel<1, 1><<<256, 512, 0, stream>>>(hid, w2t, moe, (void*)out,
                                                 pbuf, DFF / 2, DFF, H);
    // out += pbuf
    combine_kernel<<<2048, 256, 0, stream>>>(out, pbuf);
}

// Round 5
// 737.028 us; speedup vs baseline: 1.0749x; 1.0749x over previous
//
#include <hip/hip_runtime.h>
#include <hip/hip_bf16.h>
#include <hip/hip_fp16.h>

#define H 2048
#define E 8
#define DFF 8192
#define NTOK 4096
#define NB 4  // H/512 scale blocks

typedef _Float16 f16x8 __attribute__((ext_vector_type(8)));
typedef _Float16 f16x2 __attribute__((ext_vector_type(2)));
typedef float f32x4 __attribute__((ext_vector_type(4)));

#define AS1 __attribute__((address_space(1)))
#define AS3 __attribute__((address_space(3)))

__device__ __forceinline__ void gl_lds16(const void* g, void* l) {
    __builtin_amdgcn_global_load_lds((const AS1 unsigned int*)g,
                                     (AS3 unsigned int*)l, 16, 0, 0);
}

__device__ __forceinline__ float gelu_f(float x) {
    float u = 0.7978845608028654f * x * (1.0f + 0.044715f * x * x);
    float t = fabsf(u);
    float e = __expf(-2.0f * t);
    float th = (1.0f - e) / (1.0f + e);
    th = copysignf(th, u);
    return 0.5f * x * (1.0f + th);
}

// ------- fused router (fp32) + x->fp16 cast + NF4 dequant expert mix -------
// One block per token: phase 1 computes router logits (block-wide dot) and
// writes xh; phase 2 computes probs in LDS (fp16 round-trip as reference);
// phase 3 does the NF4 expert mix with int4 (16B/lane) nf4 loads and
// 2x float4 moe writes.  probs never touch global memory.
__global__ __launch_bounds__(256) void router_moe_kernel(
    const float* __restrict__ x, const float* __restrict__ rw,
    const int* __restrict__ nf4, const float* __restrict__ mean,
    const float* __restrict__ stdv, const float* __restrict__ cb,
    _Float16* __restrict__ xh, float* __restrict__ moe)
{
    int n = blockIdx.x, t = threadIdx.x;
    __shared__ float red[4][E];
    __shared__ float pr[E];
    __shared__ float cbl[32];       // 2 copies of 16-entry codebook
    __shared__ float ps[E][NB];     // prob*std
    __shared__ float cmean[NB];     // sum_e prob*mean

    // ---- phase 1: router dot + cast ----
    float acc[E];
#pragma unroll
    for (int e = 0; e < E; ++e) acc[e] = 0.f;
    const float* xr = x + (size_t)n * H;
#pragma unroll
    for (int k = 0; k < H / 256; ++k) {
        int h = t + k * 256;
        float xv = xr[h];
        xh[(size_t)n * H + h] = (_Float16)xv;
        const float4* r4 = reinterpret_cast<const float4*>(rw + (size_t)h * E);
        float4 a = r4[0], b = r4[1];
        acc[0] += xv * a.x; acc[1] += xv * a.y; acc[2] += xv * a.z; acc[3] += xv * a.w;
        acc[4] += xv * b.x; acc[5] += xv * b.y; acc[6] += xv * b.z; acc[7] += xv * b.w;
    }
#pragma unroll
    for (int e = 0; e < E; ++e) {
        float v = acc[e];
#pragma unroll
        for (int o = 32; o > 0; o >>= 1) v += __shfl_down(v, o, 64);
        acc[e] = v;
    }
    int wave = t >> 6, lane = t & 63;
    if (lane == 0) {
#pragma unroll
        for (int e = 0; e < E; ++e) red[wave][e] = acc[e];
    }
    __syncthreads();
    if (t == 0) {
        float lg[E];
        float mx = -1e30f;
#pragma unroll
        for (int e = 0; e < E; ++e) {
            lg[e] = red[0][e] + red[1][e] + red[2][e] + red[3][e];
            mx = fmaxf(mx, lg[e]);
        }
        float s = 0.f;
#pragma unroll
        for (int e = 0; e < E; ++e) { lg[e] = expf(lg[e] - mx); s += lg[e]; }
        float inv = 1.f / s;
#pragma unroll
        for (int e = 0; e < E; ++e) {
            float p = lg[e] * inv;
            pr[e] = __half2float(__float2half(p));   // fp16 round-trip
        }
    }
    __syncthreads();

    // ---- phase 2: per-block scale tables ----
    if (t < 16) { float v = cb[t]; cbl[t] = v; cbl[t + 16] = v; }
    else if (t >= 32 && t < 64) {
        int e = (t - 32) >> 2, b = t & 3;
        ps[e][b] = pr[e] * stdv[((size_t)n * E + e) * NB + b];
    } else if (t >= 64 && t < 68) {
        int b = t - 64; float s = 0.f;
        for (int e = 0; e < E; ++e)
            s += pr[e] * mean[((size_t)n * E + e) * NB + b];
        cmean[b] = s;
    }
    __syncthreads();

    // ---- phase 3: NF4 mix, int4 loads (4 words -> 8 h values / thread) ----
    int b = t >> 6;                 // h-block index, wave-uniform
    int cboff = (t & 1) << 4;
    const int4* w4 = reinterpret_cast<const int4*>(nf4 + (size_t)n * (E * H / 2));
    float o[8];
    float cm = cmean[b];
#pragma unroll
    for (int u = 0; u < 8; ++u) o[u] = cm;
#pragma unroll
    for (int e = 0; e < E; ++e) {
        int4 wv = w4[e * 256 + t];
        float pse = ps[e][b];
        int w0 = wv.x, w1 = wv.y, w2 = wv.z, w3 = wv.w;
        o[0] += pse * cbl[(w0 & 15) + cboff];
        o[1] += pse * cbl[((w0 >> 4) & 15) + cboff];
        o[2] += pse * cbl[(w1 & 15) + cboff];
        o[3] += pse * cbl[((w1 >> 4) & 15) + cboff];
        o[4] += pse * cbl[(w2 & 15) + cboff];
        o[5] += pse * cbl[((w2 >> 4) & 15) + cboff];
        o[6] += pse * cbl[(w3 & 15) + cboff];
        o[7] += pse * cbl[((w3 >> 4) & 15) + cboff];
    }
    float4* op = reinterpret_cast<float4*>(moe + (size_t)n * H + 8 * t);
    op[0] = make_float4(o[0], o[1], o[2], o[3]);
    op[1] = make_float4(o[4], o[5], o[6], o[7]);
}

// ---------------- transpose + cast fp32 [R,C] -> fp16 [C,R] ----------------
// 64x64 tiles, float4 loads (256B/row-segment), f16x2 writes (128B dst rows).
__global__ __launch_bounds__(256) void transpose_cast_kernel(
    const float* __restrict__ src, _Float16* __restrict__ dst, int R, int C)
{
    __shared__ float tile[64][65];
    int t = threadIdx.x;
    int c0 = blockIdx.x * 64, r0 = blockIdx.y * 64;
    int ct = (t & 15) * 4, rt = t >> 4;
#pragma unroll
    for (int i = 0; i < 4; ++i) {
        int r = rt + i * 16;
        float4 v = *reinterpret_cast<const float4*>(src + (size_t)(r0 + r) * C + c0 + ct);
        tile[r][ct] = v.x; tile[r][ct + 1] = v.y;
        tile[r][ct + 2] = v.z; tile[r][ct + 3] = v.w;
    }
    __syncthreads();
    int u = (t & 31) * 2, cq = t >> 5;
#pragma unroll
    for (int i = 0; i < 8; ++i) {
        int c = cq + i * 8;
        f16x2 pk;
        pk[0] = (_Float16)tile[u][c];
        pk[1] = (_Float16)tile[u + 1][c];
        *reinterpret_cast<f16x2*>(dst + (size_t)(c0 + c) * R + r0 + u) = pk;
    }
}

// ---------------- fp16 MFMA GEMM: m201-geometry 8-phase 256x256 ----------
// (unchanged from round 3 — best measured GEMM structure this session)
template <int EPI, int MAP>
__global__ __launch_bounds__(512, 2) void gemm8p_kernel(
    const _Float16* __restrict__ A, const _Float16* __restrict__ Bt,
    const float* __restrict__ addsrc, void* __restrict__ outv,
    float* __restrict__ aux, int K, int LDK, int N)
{
    __shared__ uint4 lds_u4[131072 / 16];   // 128 KB
    char* lds = (char*)lds_u4;
    char* R0 = lds;
    char* R1 = lds + 65536;

    int t = threadIdx.x;
    int id = blockIdx.x;
    int xcd = id & 7, chunk = id >> 3;
    int by, bx, ks = 0;
    if constexpr (MAP == 0) {
        by = (xcd & 1) * 8 + (chunk & 7);
        bx = (xcd >> 1) * 8 + (chunk >> 3);
    } else {
        by = (xcd >> 1) * 4 + (chunk & 3);
        bx = (xcd & 1) * 4 + ((chunk >> 2) & 3);
        ks = chunk >> 4;
    }
    int m0 = by * 256, n0 = bx * 256;
    int koff = ks * K;

    const unsigned short* sA = (const unsigned short*)A
        + (size_t)(m0 + (t & 255)) * LDK + koff + (t >> 8) * 8;
    const unsigned short* sB = (const unsigned short*)Bt
        + (size_t)(n0 + (t & 255)) * LDK + koff + (t >> 8) * 8;
    unsigned dstT = (unsigned)t * 16;

    int lane = t & 63, wave = t >> 6;
    int wr = wave >> 2, wc = wave & 3;      // 2M x 4N
    int mb = wr * 128, nb = wc * 64;
    int q = lane >> 4, m16 = lane & 15;

    unsigned aBase = (unsigned)(mb + m16) * 16u;
    unsigned bBase = 32768u + (unsigned)(nb + m16) * 16u;

    f32x4 acc[8][4] = {};
    f16x8 af[8], bL[4], bH[4];

#define STG_A(Wb, T, s) do { \
    gl_lds16(sA + (size_t)(T) * 64 + (s) * 16,      (Wb) + (s) * 8192 + dstT); \
    gl_lds16(sA + (size_t)(T) * 64 + (s) * 16 + 16, (Wb) + (s) * 8192 + 8192 + dstT); } while (0)
#define STG_B(Wb, T, s) do { \
    gl_lds16(sB + (size_t)(T) * 64 + (s) * 16,      (Wb) + 32768 + (s) * 8192 + dstT); \
    gl_lds16(sB + (size_t)(T) * 64 + (s) * 16 + 16, (Wb) + 32768 + (s) * 8192 + 8192 + dstT); } while (0)
#define RD_A(Rb, ih) do { \
    _Pragma("unroll") for (int il = 0; il < 4; ++il) \
    _Pragma("unroll") for (int kh = 0; kh < 2; ++kh) \
        af[il * 2 + kh] = *(const f16x8*)((Rb) + aBase + \
            (unsigned)(kh * 16384 + q * 4096 + (ih) * 1024 + il * 256)); } while (0)
#define RD_B(Rb, jh, dst) do { \
    _Pragma("unroll") for (int jl = 0; jl < 2; ++jl) \
    _Pragma("unroll") for (int kh = 0; kh < 2; ++kh) \
        dst[jl * 2 + kh] = *(const f16x8*)((Rb) + bBase + \
            (unsigned)(kh * 16384 + q * 4096 + (jh) * 512 + jl * 256)); } while (0)
#define MMQ(ih, bfr, j0) do { \
    __builtin_amdgcn_s_setprio(1); \
    _Pragma("unroll") for (int il = 0; il < 4; ++il) \
    _Pragma("unroll") for (int jl = 0; jl < 2; ++jl) \
    _Pragma("unroll") for (int kh = 0; kh < 2; ++kh) \
        acc[(ih) * 4 + il][(j0) + jl] = __builtin_amdgcn_mfma_f32_16x16x32_f16( \
            af[il * 2 + kh], bfr[jl * 2 + kh], acc[(ih) * 4 + il][(j0) + jl], 0, 0, 0); \
    __builtin_amdgcn_s_setprio(0); } while (0)
#define BARR  asm volatile("s_barrier" ::: "memory")
#define LGKM0 asm volatile("s_waitcnt lgkmcnt(0)" ::: "memory")

    // prologue: tile 0 fully -> buf0 (8 loads) + tile 1 chunk A01 -> buf1 (2)
    STG_A(R0, 0, 0); STG_A(R0, 0, 2);
    STG_B(R0, 0, 0); STG_B(R0, 0, 2);
    STG_A(R1, 1, 0);
    asm volatile("s_waitcnt vmcnt(2)" ::: "memory");  // tile 0 landed
    BARR;

    int NIT = K / 128;
    for (int i = 0; i < NIT; ++i) {
        int T0 = 2 * i, T1 = 2 * i + 1;
        bool more = (i + 1 < NIT);

        // ---- p1: stage t1.A23->buf1 | read t0 A-iL + B-jL | mfma (iL,jL)
        STG_A(R1, T1, 2);
        RD_A(R0, 0); RD_B(R0, 0, bL);
        BARR; LGKM0;
        MMQ(0, bL, 0);
        BARR;
        // ---- p2: stage t1.B01 | read t0 B-jH | mfma (iL,jH)
        STG_B(R1, T1, 0);
        RD_B(R0, 1, bH);
        BARR; LGKM0;
        MMQ(0, bH, 2);
        BARR;
        // ---- p3: stage t1.B23 | read t0 A-iH | mfma (iH,jH)
        STG_B(R1, T1, 2);
        RD_A(R0, 1);
        BARR; LGKM0;
        MMQ(1, bH, 2);
        BARR;
        // ---- p4: stage t2.A01->buf0 | mfma (iH,jL) | vmcnt(2)
        if (more) STG_A(R0, T0 + 2, 0);
        MMQ(1, bL, 0);
        if (more) asm volatile("s_waitcnt vmcnt(2)" ::: "memory");
        else      asm volatile("s_waitcnt vmcnt(0)" ::: "memory");
        BARR;

        // ---- p5: stage t2.A23 | read t1 A-iL + B-jL | mfma (iL,jL)
        if (more) STG_A(R0, T0 + 2, 2);
        RD_A(R1, 0); RD_B(R1, 0, bL);
        BARR; LGKM0;
        MMQ(0, bL, 0);
        BARR;
        // ---- p6: stage t2.B01 | read t1 B-jH | mfma (iL,jH)
        if (more) STG_B(R0, T0 + 2, 0);
        RD_B(R1, 1, bH);
        BARR; LGKM0;
        MMQ(0, bH, 2);
        BARR;
        // ---- p7: stage t2.B23 | read t1 A-iH | mfma (iH,jH)
        if (more) STG_B(R0, T0 + 2, 2);
        RD_A(R1, 1);
        BARR; LGKM0;
        MMQ(1, bH, 2);
        BARR;
        // ---- p8: stage t3.A01->buf1 | mfma (iH,jL) | vmcnt(2)
        if (more) STG_A(R1, T1 + 2, 0);
        MMQ(1, bL, 0);
        if (more) asm volatile("s_waitcnt vmcnt(2)" ::: "memory");
        else      asm volatile("s_waitcnt vmcnt(0)" ::: "memory");
        BARR;
    }

    // epilogue (verified C/D mapping: col=lane&15, row=q*4+rix)
#pragma unroll
    for (int i = 0; i < 8; ++i)
#pragma unroll
        for (int j = 0; j < 4; ++j) {
            int row = m0 + mb + i * 16 + q * 4;
            int col = n0 + nb + j * 16 + m16;
#pragma unroll
            for (int rix = 0; rix < 4; ++rix) {
                float v = acc[i][j][rix];
                size_t o = (size_t)(row + rix) * N + col;
                if constexpr (EPI == 0) {
                    ((_Float16*)outv)[o] = (_Float16)gelu_f(v);
                } else {
                    if (ks == 0) ((float*)outv)[o] = v + addsrc[o];
                    else         aux[o] = v;
                }
            }
        }
#undef STG_A
#undef STG_B
#undef RD_A
#undef RD_B
#undef MMQ
#undef BARR
#undef LGKM0
}

// ---------------- split-K combine: out += part ----------------
__global__ __launch_bounds__(256) void combine_kernel(
    float* __restrict__ out, const float* __restrict__ part)
{
    size_t base = (size_t)blockIdx.x * 256 + threadIdx.x;
    const float4* p4 = (const float4*)part;
    float4* o4 = (float4*)out;
#pragma unroll
    for (int s = 0; s < 4; ++s) {
        size_t i = base + (size_t)s * 524288;   // 2048*256
        float4 a = o4[i], b = p4[i];
        o4[i] = make_float4(a.x + b.x, a.y + b.y, a.z + b.z, a.w + b.w);
    }
}

extern "C" void kernel_launch(void* const* d_in, const int* in_sizes, int n_in,
                              void* d_out, int out_size, void* d_ws, size_t ws_size,
                              hipStream_t stream) {
    const float* x    = (const float*)d_in[0];
    const float* rw   = (const float*)d_in[1];
    const int*   nf4  = (const int*)d_in[2];
    const float* mean = (const float*)d_in[3];
    const float* stdv = (const float*)d_in[4];
    const float* cb   = (const float*)d_in[5];
    const float* w1   = (const float*)d_in[6];
    const float* w2   = (const float*)d_in[7];
    float* out = (float*)d_out;

    char* ws = (char*)d_ws;
    float* moe        = (float*)(ws + 131072);               // 32 MB
    _Float16* xh      = (_Float16*)(ws + 33685504);          // 16 MB  [NTOK,H]
    _Float16* w1t     = (_Float16*)(ws + 50462720);          // 32 MB  [DFF,H]
    _Float16* w2t     = (_Float16*)(ws + 84017152);          // 32 MB  [H,DFF]
    _Float16* hid     = (_Float16*)(ws + 117571584);         // 64 MB  [NTOK,DFF]
    // split-K partial buffer overlays w1t (dead after GEMM1): 32 MB fp32
    float* pbuf       = (float*)(ws + 50462720);

    // fused router + cast + NF4 expert mix (probs stay in LDS)
    router_moe_kernel<<<NTOK, 256, 0, stream>>>(x, rw, nf4, mean, stdv, cb, xh, moe);
    transpose_cast_kernel<<<dim3(DFF / 64, H / 64), 256, 0, stream>>>(w1, w1t, H, DFF);
    transpose_cast_kernel<<<dim3(H / 64, DFF / 64), 256, 0, stream>>>(w2, w2t, DFF, H);
    // hidden = gelu(x @ w1): 256x256 tiles, grid 16x32 -> 512 blocks (2 rounds)
    gemm8p_kernel<0, 0><<<512, 512, 0, stream>>>(xh, w1t, nullptr, (void*)hid,
                                                 nullptr, H, H, DFF);
    // out = moe + hidden @ w2, split-K=2: 256 blocks (1/CU)
    gemm8p_kernel<1, 1><<<256, 512, 0, stream>>>(hid, w2t, moe, (void*)out,
                                                 pbuf, DFF / 2, DFF, H);
    // out += pbuf
    combine_kernel<<<2048, 256, 0, stream>>>(out, pbuf);
}

// Round 6
// 724.812 us; speedup vs baseline: 1.0930x; 1.0169x over previous
//
#include <hip/hip_runtime.h>
#include <hip/hip_bf16.h>
#include <hip/hip_fp16.h>

#define H 2048
#define E 8
#define DFF 8192
#define NTOK 4096
#define NB 4  // H/512 scale blocks

typedef _Float16 f16x8 __attribute__((ext_vector_type(8)));
typedef _Float16 f16x2 __attribute__((ext_vector_type(2)));
typedef float f32x4 __attribute__((ext_vector_type(4)));

#define AS1 __attribute__((address_space(1)))
#define AS3 __attribute__((address_space(3)))

__device__ __forceinline__ void gl_lds16(const void* g, void* l) {
    __builtin_amdgcn_global_load_lds((const AS1 unsigned int*)g,
                                     (AS3 unsigned int*)l, 16, 0, 0);
}

__device__ __forceinline__ float gelu_f(float x) {
    float u = 0.7978845608028654f * x * (1.0f + 0.044715f * x * x);
    float t = fabsf(u);
    float e = __expf(-2.0f * t);
    float th = (1.0f - e) / (1.0f + e);
    th = copysignf(th, u);
    return 0.5f * x * (1.0f + th);
}

// ------- fused router (fp32) + x->fp16 cast + NF4 dequant expert mix -------
__global__ __launch_bounds__(256) void router_moe_kernel(
    const float* __restrict__ x, const float* __restrict__ rw,
    const int* __restrict__ nf4, const float* __restrict__ mean,
    const float* __restrict__ stdv, const float* __restrict__ cb,
    _Float16* __restrict__ xh, float* __restrict__ moe)
{
    int n = blockIdx.x, t = threadIdx.x;
    __shared__ float red[4][E];
    __shared__ float pr[E];
    __shared__ float cbl[32];       // 2 copies of 16-entry codebook
    __shared__ float ps[E][NB];     // prob*std
    __shared__ float cmean[NB];     // sum_e prob*mean

    // ---- phase 1: router dot + cast ----
    float acc[E];
#pragma unroll
    for (int e = 0; e < E; ++e) acc[e] = 0.f;
    const float* xr = x + (size_t)n * H;
#pragma unroll
    for (int k = 0; k < H / 256; ++k) {
        int h = t + k * 256;
        float xv = xr[h];
        xh[(size_t)n * H + h] = (_Float16)xv;
        const float4* r4 = reinterpret_cast<const float4*>(rw + (size_t)h * E);
        float4 a = r4[0], b = r4[1];
        acc[0] += xv * a.x; acc[1] += xv * a.y; acc[2] += xv * a.z; acc[3] += xv * a.w;
        acc[4] += xv * b.x; acc[5] += xv * b.y; acc[6] += xv * b.z; acc[7] += xv * b.w;
    }
#pragma unroll
    for (int e = 0; e < E; ++e) {
        float v = acc[e];
#pragma unroll
        for (int o = 32; o > 0; o >>= 1) v += __shfl_down(v, o, 64);
        acc[e] = v;
    }
    int wave = t >> 6, lane = t & 63;
    if (lane == 0) {
#pragma unroll
        for (int e = 0; e < E; ++e) red[wave][e] = acc[e];
    }
    __syncthreads();
    if (t == 0) {
        float lg[E];
        float mx = -1e30f;
#pragma unroll
        for (int e = 0; e < E; ++e) {
            lg[e] = red[0][e] + red[1][e] + red[2][e] + red[3][e];
            mx = fmaxf(mx, lg[e]);
        }
        float s = 0.f;
#pragma unroll
        for (int e = 0; e < E; ++e) { lg[e] = expf(lg[e] - mx); s += lg[e]; }
        float inv = 1.f / s;
#pragma unroll
        for (int e = 0; e < E; ++e) {
            float p = lg[e] * inv;
            pr[e] = __half2float(__float2half(p));   // fp16 round-trip
        }
    }
    __syncthreads();

    // ---- phase 2: per-block scale tables ----
    if (t < 16) { float v = cb[t]; cbl[t] = v; cbl[t + 16] = v; }
    else if (t >= 32 && t < 64) {
        int e = (t - 32) >> 2, b = t & 3;
        ps[e][b] = pr[e] * stdv[((size_t)n * E + e) * NB + b];
    } else if (t >= 64 && t < 68) {
        int b = t - 64; float s = 0.f;
        for (int e = 0; e < E; ++e)
            s += pr[e] * mean[((size_t)n * E + e) * NB + b];
        cmean[b] = s;
    }
    __syncthreads();

    // ---- phase 3: NF4 mix, int4 loads (4 words -> 8 h values / thread) ----
    int b = t >> 6;                 // h-block index, wave-uniform
    int cboff = (t & 1) << 4;
    const int4* w4 = reinterpret_cast<const int4*>(nf4 + (size_t)n * (E * H / 2));
    float o[8];
    float cm = cmean[b];
#pragma unroll
    for (int u = 0; u < 8; ++u) o[u] = cm;
#pragma unroll
    for (int e = 0; e < E; ++e) {
        int4 wv = w4[e * 256 + t];
        float pse = ps[e][b];
        int w0 = wv.x, w1 = wv.y, w2 = wv.z, w3 = wv.w;
        o[0] += pse * cbl[(w0 & 15) + cboff];
        o[1] += pse * cbl[((w0 >> 4) & 15) + cboff];
        o[2] += pse * cbl[(w1 & 15) + cboff];
        o[3] += pse * cbl[((w1 >> 4) & 15) + cboff];
        o[4] += pse * cbl[(w2 & 15) + cboff];
        o[5] += pse * cbl[((w2 >> 4) & 15) + cboff];
        o[6] += pse * cbl[(w3 & 15) + cboff];
        o[7] += pse * cbl[((w3 >> 4) & 15) + cboff];
    }
    float4* op = reinterpret_cast<float4*>(moe + (size_t)n * H + 8 * t);
    op[0] = make_float4(o[0], o[1], o[2], o[3]);
    op[1] = make_float4(o[4], o[5], o[6], o[7]);
}

// ---------------- transpose + cast fp32 [R,C] -> fp16 [C,R] ----------------
__global__ __launch_bounds__(256) void transpose_cast_kernel(
    const float* __restrict__ src, _Float16* __restrict__ dst, int R, int C)
{
    __shared__ float tile[64][65];
    int t = threadIdx.x;
    int c0 = blockIdx.x * 64, r0 = blockIdx.y * 64;
    int ct = (t & 15) * 4, rt = t >> 4;
#pragma unroll
    for (int i = 0; i < 4; ++i) {
        int r = rt + i * 16;
        float4 v = *reinterpret_cast<const float4*>(src + (size_t)(r0 + r) * C + c0 + ct);
        tile[r][ct] = v.x; tile[r][ct + 1] = v.y;
        tile[r][ct + 2] = v.z; tile[r][ct + 3] = v.w;
    }
    __syncthreads();
    int u = (t & 31) * 2, cq = t >> 5;
#pragma unroll
    for (int i = 0; i < 8; ++i) {
        int c = cq + i * 8;
        f16x2 pk;
        pk[0] = (_Float16)tile[u][c];
        pk[1] = (_Float16)tile[u + 1][c];
        *reinterpret_cast<f16x2*>(dst + (size_t)(c0 + c) * R + r0 + u) = pk;
    }
}

// ---- fp16 MFMA GEMM: 256x256, BK=32, 5-buffer deep pipeline (160 KB) ----
// C = A[M,K] * Bt[N,K]^T.  512 thr / 8 waves (2M x 4N, per-wave 128x64,
// acc[8][4]).  BK=32 -> tile buffer = A 16KB + B 16KB = 32 KB; FIVE rotating
// buffers (160 KB LDS, full pool; 144 KB already ran in round 2).
// k-seg-major layout (conflict-free ds_read_b128; per-lane GLOBAL address
// provides the permutation, global_load_lds writes linearly).
// Per tile, 2 phases of 16 MFMA (same phase/barrier density per unit K as
// the BK=64 8-phase):
//   P1(t): read B(t)(4) + A-iL(t)(4); stage A(t+3); bar; lgkm0;
//          setprio1; 16 MFMA (iL x jAll); setprio0; bar
//   P2(t): read A-iH(t)(4); stage B(t+3); bar; lgkm0;
//          setprio1; 16 MFMA (iH x jAll); setprio0; vmcnt(8); bar
// DEEP counted pipeline: the vmcnt(8) at end of tile t drains only chunks
// staged >= 4 phases earlier (B(t+1) was staged at P2(t-2)); 8 loads
// (2 full tiles) remain in flight across every barrier.  Buffer written by
// stage(t+3) was last read 4 phases ago (>=3 barriers separation).
// EPI 0: out = f16(gelu(acc)).
// EPI 1: split-K pair: ks==0 -> out = acc + addsrc; ks==1 -> aux = acc.
template <int EPI, int MAP>
__global__ __launch_bounds__(512, 2) void gemm5b_kernel(
    const _Float16* __restrict__ A, const _Float16* __restrict__ Bt,
    const float* __restrict__ addsrc, void* __restrict__ outv,
    float* __restrict__ aux, int K, int LDK, int N)
{
    __shared__ uint4 lds_u4[163840 / 16];   // 160 KB = 5 x 32 KB
    char* lds = (char*)lds_u4;

    int t = threadIdx.x;
    int id = blockIdx.x;
    int xcd = id & 7, chunk = id >> 3;
    int by, bx, ks = 0;
    if constexpr (MAP == 0) {
        by = (xcd & 1) * 8 + (chunk & 7);
        bx = (xcd >> 1) * 8 + (chunk >> 3);
    } else {
        by = (xcd >> 1) * 4 + (chunk & 3);
        bx = (xcd & 1) * 4 + ((chunk >> 2) & 3);
        ks = chunk >> 4;
    }
    int m0 = by * 256, n0 = bx * 256;
    int koff = ks * K;

    // staging sources: thread t -> row (t&255), kseg (t>>8) of the tile
    const unsigned short* sA = (const unsigned short*)A
        + (size_t)(m0 + (t & 255)) * LDK + koff + (t >> 8) * 8;
    const unsigned short* sB = (const unsigned short*)Bt
        + (size_t)(n0 + (t & 255)) * LDK + koff + (t >> 8) * 8;
    unsigned dstT = (unsigned)t * 16;

    int lane = t & 63, wave = t >> 6;
    int wr = wave >> 2, wc = wave & 3;      // 2M x 4N
    int mb = wr * 128, nb = wc * 64;
    int q = lane >> 4, m16 = lane & 15;

    // LDS read offsets within a 32 KB buffer: A at 0, B at 16384;
    // addr = region + kseg(q)*4096 + row*16
    unsigned aOff = (unsigned)(q * 4096 + (mb + m16) * 16);
    unsigned bOff = (unsigned)(16384 + q * 4096 + (nb + m16) * 16);

    f32x4 acc[8][4] = {};
    f16x8 afL[4], afH[4], bf[4];

#define STG_A(Wb, T) do { \
    gl_lds16(sA + (size_t)(T) * 32,      (Wb) + dstT); \
    gl_lds16(sA + (size_t)(T) * 32 + 16, (Wb) + 8192 + dstT); } while (0)
#define STG_B(Wb, T) do { \
    gl_lds16(sB + (size_t)(T) * 32,      (Wb) + 16384 + dstT); \
    gl_lds16(sB + (size_t)(T) * 32 + 16, (Wb) + 16384 + 8192 + dstT); } while (0)
#define RD_B(Rb) do { \
    _Pragma("unroll") for (int jl = 0; jl < 4; ++jl) \
        bf[jl] = *(const f16x8*)((Rb) + bOff + jl * 256); } while (0)
#define RD_AL(Rb) do { \
    _Pragma("unroll") for (int il = 0; il < 4; ++il) \
        afL[il] = *(const f16x8*)((Rb) + aOff + il * 256); } while (0)
#define RD_AH(Rb) do { \
    _Pragma("unroll") for (int il = 0; il < 4; ++il) \
        afH[il] = *(const f16x8*)((Rb) + aOff + 1024 + il * 256); } while (0)
#define MM(i0, afr) do { \
    __builtin_amdgcn_s_setprio(1); \
    _Pragma("unroll") for (int il = 0; il < 4; ++il) \
    _Pragma("unroll") for (int jl = 0; jl < 4; ++jl) \
        acc[(i0) + il][jl] = __builtin_amdgcn_mfma_f32_16x16x32_f16( \
            afr[il], bf[jl], acc[(i0) + il][jl], 0, 0, 0); \
    __builtin_amdgcn_s_setprio(0); } while (0)
#define BARR  asm volatile("s_barrier" ::: "memory")
#define LGKM0 asm volatile("s_waitcnt lgkmcnt(0)" ::: "memory")

    // prologue: stage tiles 0,1,2 -> bufs 0,1,2 (12 loads); drain tile 0
    STG_A(lds,         0); STG_B(lds,         0);
    STG_A(lds + 32768, 1); STG_B(lds + 32768, 1);
    STG_A(lds + 65536, 2); STG_B(lds + 65536, 2);
    asm volatile("s_waitcnt vmcnt(8)" ::: "memory");   // tile 0 landed
    BARR;

    int NT = K / 32;
    unsigned rb = 0, wb = 3 * 32768;
    for (int T = 0; T < NT; ++T) {
        char* R = lds + rb;
        char* W = lds + wb;
        bool st = (T + 3 < NT);

        // ---- P1(t): B + A-iL reads | stage A(t+3) | MFMA iL ----
        RD_B(R); RD_AL(R);
        if (st) STG_A(W, T + 3);
        BARR; LGKM0;
        MM(0, afL);
        BARR;
        // ---- P2(t): A-iH reads | stage B(t+3) | MFMA iH | counted drain ----
        RD_AH(R);
        if (st) STG_B(W, T + 3);
        BARR; LGKM0;
        MM(4, afH);
        if (st) asm volatile("s_waitcnt vmcnt(8)" ::: "memory");  // t+1 landed
        else    asm volatile("s_waitcnt vmcnt(0)" ::: "memory");
        BARR;

        rb += 32768; if (rb == 163840) rb = 0;
        wb += 32768; if (wb == 163840) wb = 0;
    }

    // epilogue (verified C/D mapping: col=lane&15, row=q*4+rix)
#pragma unroll
    for (int i = 0; i < 8; ++i)
#pragma unroll
        for (int j = 0; j < 4; ++j) {
            int row = m0 + mb + i * 16 + q * 4;
            int col = n0 + nb + j * 16 + m16;
#pragma unroll
            for (int rix = 0; rix < 4; ++rix) {
                float v = acc[i][j][rix];
                size_t o = (size_t)(row + rix) * N + col;
                if constexpr (EPI == 0) {
                    ((_Float16*)outv)[o] = (_Float16)gelu_f(v);
                } else {
                    if (ks == 0) ((float*)outv)[o] = v + addsrc[o];
                    else         aux[o] = v;
                }
            }
        }
#undef STG_A
#undef STG_B
#undef RD_B
#undef RD_AL
#undef RD_AH
#undef MM
#undef BARR
#undef LGKM0
}

// ---------------- split-K combine: out += part ----------------
__global__ __launch_bounds__(256) void combine_kernel(
    float* __restrict__ out, const float* __restrict__ part)
{
    size_t base = (size_t)blockIdx.x * 256 + threadIdx.x;
    const float4* p4 = (const float4*)part;
    float4* o4 = (float4*)out;
#pragma unroll
    for (int s = 0; s < 4; ++s) {
        size_t i = base + (size_t)s * 524288;   // 2048*256
        float4 a = o4[i], b = p4[i];
        o4[i] = make_float4(a.x + b.x, a.y + b.y, a.z + b.z, a.w + b.w);
    }
}

extern "C" void kernel_launch(void* const* d_in, const int* in_sizes, int n_in,
                              void* d_out, int out_size, void* d_ws, size_t ws_size,
                              hipStream_t stream) {
    const float* x    = (const float*)d_in[0];
    const float* rw   = (const float*)d_in[1];
    const int*   nf4  = (const int*)d_in[2];
    const float* mean = (const float*)d_in[3];
    const float* stdv = (const float*)d_in[4];
    const float* cb   = (const float*)d_in[5];
    const float* w1   = (const float*)d_in[6];
    const float* w2   = (const float*)d_in[7];
    float* out = (float*)d_out;

    char* ws = (char*)d_ws;
    float* moe        = (float*)(ws + 131072);               // 32 MB
    _Float16* xh      = (_Float16*)(ws + 33685504);          // 16 MB  [NTOK,H]
    _Float16* w1t     = (_Float16*)(ws + 50462720);          // 32 MB  [DFF,H]
    _Float16* w2t     = (_Float16*)(ws + 84017152);          // 32 MB  [H,DFF]
    _Float16* hid     = (_Float16*)(ws + 117571584);         // 64 MB  [NTOK,DFF]
    // split-K partial buffer overlays w1t (dead after GEMM1): 32 MB fp32
    float* pbuf       = (float*)(ws + 50462720);

    // fused router + cast + NF4 expert mix (probs stay in LDS)
    router_moe_kernel<<<NTOK, 256, 0, stream>>>(x, rw, nf4, mean, stdv, cb, xh, moe);
    transpose_cast_kernel<<<dim3(DFF / 64, H / 64), 256, 0, stream>>>(w1, w1t, H, DFF);
    transpose_cast_kernel<<<dim3(H / 64, DFF / 64), 256, 0, stream>>>(w2, w2t, DFF, H);
    // hidden = gelu(x @ w1): 256x256 tiles, grid 16x32 -> 512 blocks (2 rounds)
    gemm5b_kernel<0, 0><<<512, 512, 0, stream>>>(xh, w1t, nullptr, (void*)hid,
                                                 nullptr, H, H, DFF);
    // out = moe + hidden @ w2, split-K=2: 256 blocks (1/CU)
    gemm5b_kernel<1, 1><<<256, 512, 0, stream>>>(hid, w2t, moe, (void*)out,
                                                 pbuf, DFF / 2, DFF, H);
    // out += pbuf
    combine_kernel<<<2048, 256, 0, stream>>>(out, pbuf);
}